// Round 6
// baseline (296.200 us; speedup 1.0000x reference)
//
#include <hip/hip_runtime.h>
#include <math.h>

// Problem constants
#define NB     64
#define CC     256
#define TT     64
#define VV     25
#define HID    16
#define NG     5
#define ROWF   1600         // floats per (n,c) pair = T*V
#define ROWF4  400          // float4 per (n,c) pair
#define PAIRS  4            // pairs per chunk (one per wave)
#define CHUNKS 4            // chunks per block -> 16 pairs per block
#define BPG    16           // blocks per n-group (16 * 16 pairs = 256 = CC)
#define NBLK   (NB * BPG)   // 1024 blocks — co-residency PROVEN in R3

// torso joints {0,1,2,3,20} as a bitmask
#define TORSO_MASK 0x10000Fu

// output joint position -> source joint (concat order: TORSO, LH, LL, RH, RL)
__constant__ int SRC_J[25] = {0,1,2,3,20,  8,9,10,11,23,24,  16,17,18,19,  4,5,6,7,21,22,  12,13,14,15};
// output joint position -> group index
__constant__ int GRP_J[25] = {0,0,0,0,0,   1,1,1,1,1,1,      2,2,2,2,      3,3,3,3,3,3,   4,4,4,4};

// Agent-scope (device-coherent) access for cross-block data (spans XCDs).
__device__ inline void st_agent(float* p, float v) {
    __hip_atomic_store(p, v, __ATOMIC_RELAXED, __HIP_MEMORY_SCOPE_AGENT);
}
__device__ inline float ld_agent(const float* p) {
    return __hip_atomic_load(p, __ATOMIC_RELAXED, __HIP_MEMORY_SCOPE_AGENT);
}

__global__ __launch_bounds__(256, 4)
void fused_kernel(const float4* __restrict__ x4,
                  const float* __restrict__ W1s,   // (5,16,256)
                  const float* __restrict__ b1s,   // (5,16)
                  const float* __restrict__ W2s,   // (5,256,16)
                  const float* __restrict__ b2s,   // (5,256)
                  float4* __restrict__ out4,
                  float* __restrict__ ws_avg,      // N*C
                  float* __restrict__ ws_max,      // N*C
                  unsigned* __restrict__ cnt) {    // NB arrival counters (zeroed)
    __shared__ __align__(16) float xt[PAIRS * ROWF];   // 25.6 KB (one chunk)
    __shared__ __align__(16) float sAvg[CC];
    __shared__ __align__(16) float sMax[CC];
    __shared__ float sHA[NG * HID];
    __shared__ float sHM[NG * HID];
    __shared__ float sg[CHUNKS * PAIRS * NG];          // 80 gates (this block's 16 pairs)
    __shared__ uint2 sLut4[VV];

    const int tid  = threadIdx.x;
    const int b    = blockIdx.x;
    const int w    = tid >> 6;          // wave = local pair within chunk
    const int lane = tid & 63;
    const int n    = b >> 4;            // batch index (16 blocks per n)
    const int sub  = b & 15;            // block index within group
    const int pairbase = n * CC + sub * (CHUNKS * PAIRS);  // first of 16 pairs

    // Packed perm LUT (R5-proven): entry[p0] = 4x 16-bit fields
    // (SRC_J[p] + 25*row_wrap) | (GRP_J[p] << 8) for positions p0..p0+3.
    if (tid < VV) {
        unsigned lo = 0, hi = 0;
        #pragma unroll
        for (int j = 0; j < 4; ++j) {
            const int pp   = tid + j;
            const int wrap = (pp >= VV) ? 1 : 0;
            const int pm   = pp - VV * wrap;
            const unsigned e = (unsigned)(SRC_J[pm] + VV * wrap) | ((unsigned)GRP_J[pm] << 8);
            if (j < 2) lo |= e << (16 * j);
            else       hi |= e << (16 * (j - 2));
        }
        sLut4[tid] = make_uint2(lo, hi);
    }

    // ---------- Phase 1: pool all 4 chunks (keep only chunk 3 in LDS) ----------
    // Each wave touches only its own LDS slice -> no cross-wave hazard, no syncs.
    #pragma unroll
    for (int ch = 0; ch < CHUNKS; ++ch) {
        const int pair  = pairbase + ch * PAIRS + w;
        const int base4 = pair * ROWF4;
        float4* xtw = reinterpret_cast<float4*>(xt + w * ROWF);
        float s = 0.0f;
        float m = -3.4e38f;
        for (int i = lane; i < ROWF4; i += 64) {
            float4 v = x4[base4 + i];
            if (ch == CHUNKS - 1) xtw[i] = v;     // resolved statically per unroll
            const int e = 4 * i;
            int j = e % 25;
            float vals[4] = {v.x, v.y, v.z, v.w};
            #pragma unroll
            for (int k = 0; k < 4; ++k) {
                int jj = j + k;
                if (jj >= 25) jj -= 25;
                if ((TORSO_MASK >> jj) & 1u) {
                    s += vals[k];
                    m = fmaxf(m, vals[k]);
                }
            }
        }
        #pragma unroll
        for (int off = 32; off >= 1; off >>= 1) {
            s += __shfl_xor(s, off, 64);
            m = fmaxf(m, __shfl_xor(m, off, 64));
        }
        if (lane == 0) {
            st_agent(ws_avg + pair, s * (1.0f / (TT * 5)));
            st_agent(ws_max + pair, m);
        }
    }

    // ---------- Group barrier: wait for this n's 16 blocks ----------
    __syncthreads();
    if (tid == 0) {
        __hip_atomic_fetch_add(cnt + n, 1u, __ATOMIC_RELEASE, __HIP_MEMORY_SCOPE_AGENT);
        while (__hip_atomic_load(cnt + n, __ATOMIC_ACQUIRE, __HIP_MEMORY_SCOPE_AGENT) < BPG) {
            __builtin_amdgcn_s_sleep(8);
        }
    }
    __syncthreads();

    // ---------- Phase 2: gates for this n (redundant per block, cheap) ----------
    sAvg[tid] = ld_agent(ws_avg + n * CC + tid);
    sMax[tid] = ld_agent(ws_max + n * CC + tid);
    __syncthreads();

    if (tid < 2 * NG * HID) {              // 160 threads: hidden units, both pools
        const int type = tid / (NG * HID); // 0 = avg, 1 = max
        const int rem  = tid % (NG * HID); // f*16 + j
        const float4* p  = reinterpret_cast<const float4*>(type ? sMax : sAvg);
        const float4* wv = reinterpret_cast<const float4*>(W1s + rem * CC);
        float h = b1s[rem];
        #pragma unroll 8
        for (int c4 = 0; c4 < CC / 4; ++c4) {
            float4 a = wv[c4], q = p[c4];
            h += a.x * q.x + a.y * q.y + a.z * q.z + a.w * q.w;
        }
        h = fmaxf(h, 0.0f);
        if (type) sHM[rem] = h; else sHA[rem] = h;
    }
    __syncthreads();

    if (tid < CHUNKS * PAIRS * NG) {       // 80 threads: one gate each
        const int lp = tid / NG;           // local pair 0..15  (= ch*4 + wave)
        const int f  = tid % NG;
        const int cch = (pairbase + lp) & (CC - 1);
        const float4* w2 = reinterpret_cast<const float4*>(W2s + (f * CC + cch) * HID);
        float g = 2.0f * b2s[f * CC + cch];
        #pragma unroll
        for (int j4 = 0; j4 < HID / 4; ++j4) {
            float4 wq = w2[j4];
            const int jb = f * HID + j4 * 4;
            g += wq.x * (sHA[jb + 0] + sHM[jb + 0]);
            g += wq.y * (sHA[jb + 1] + sHM[jb + 1]);
            g += wq.z * (sHA[jb + 2] + sHM[jb + 2]);
            g += wq.w * (sHA[jb + 3] + sHM[jb + 3]);
        }
        sg[tid] = 1.0f / (1.0f + expf(-g));
    }
    __syncthreads();

    // ---------- Phase 3: apply. Chunk 3 first (resident), then 0,1,2 (L3-hot restage) ----------
    #pragma unroll
    for (int step = 0; step < CHUNKS; ++step) {
        const int ch = (step == 0) ? (CHUNKS - 1) : (step - 1);   // 3,0,1,2
        const int pair  = pairbase + ch * PAIRS + w;
        const int base4 = pair * ROWF4;
        float4* xtw = reinterpret_cast<float4*>(xt + w * ROWF);

        if (step != 0) {
            __syncthreads();   // cheap safety vs LDS reorder across chunks
            for (int i = lane; i < ROWF4; i += 64) xtw[i] = x4[base4 + i];
            __syncthreads();
        }

        const int gbase = (ch * PAIRS + w) * NG;
        const float g0 = sg[gbase + 0];
        const float g1 = sg[gbase + 1];
        const float g2 = sg[gbase + 2];
        const float g3 = sg[gbase + 3];
        const float g4 = sg[gbase + 4];

        const float* lrow = xt + w * ROWF;
        #pragma unroll
        for (int k = 0; k < 7; ++k) {
            const int il = 64 * k + lane;          // float4 index within pair
            if (il < ROWF4) {
                const int e0   = 4 * il;
                const int row0 = e0 / VV;
                const int p0   = e0 - row0 * VV;
                const uint2 lut = sLut4[p0];       // 1 ds_read_b64 per 4 elems
                float r[4];
                #pragma unroll
                for (int j = 0; j < 4; ++j) {
                    const unsigned half   = ((j < 2) ? lut.x : lut.y) >> (16 * (j & 1));
                    const unsigned srcoff = half & 63u;       // src + 25*wrap
                    const unsigned grp    = (half >> 8) & 7u;
                    float gt = g0;
                    gt = (grp >= 1u) ? g1 : gt;
                    gt = (grp >= 2u) ? g2 : gt;
                    gt = (grp >= 3u) ? g3 : gt;
                    gt = (grp >= 4u) ? g4 : gt;
                    r[j] = lrow[row0 * VV + (int)srcoff] * gt;
                }
                out4[base4 + il] = make_float4(r[0], r[1], r[2], r[3]);
            }
        }
    }
}

extern "C" void kernel_launch(void* const* d_in, const int* in_sizes, int n_in,
                              void* d_out, int out_size, void* d_ws, size_t ws_size,
                              hipStream_t stream) {
    const float* x   = (const float*)d_in[0];
    const float* W1s = (const float*)d_in[1];
    const float* b1s = (const float*)d_in[2];
    const float* W2s = (const float*)d_in[3];
    const float* b2s = (const float*)d_in[4];

    float* avg = (float*)d_ws;                    // N*C
    float* mx  = avg + NB * CC;                   // N*C
    size_t cnt_off = ((size_t)(NB * CC * 2) * 4 + 255) & ~(size_t)255;
    unsigned* cnt = (unsigned*)((char*)d_ws + cnt_off);

    // zero the NB arrival counters (d_ws is poisoned 0xAA before every launch)
    hipMemsetAsync(cnt, 0, NB * sizeof(unsigned), stream);

    // 1024 blocks, 16 per n-group; all co-resident (R3-proven config:
    // ~28.7 KB LDS -> 5 blk/CU by LDS, launch_bounds(256,4) caps VGPRs).
    fused_kernel<<<NBLK, 256, 0, stream>>>(
        (const float4*)x, W1s, b1s, W2s, b2s,
        (float4*)d_out, avg, mx, cnt);
}